// Round 1
// baseline (281.505 us; speedup 1.0000x reference)
//
#include <hip/hip_runtime.h>
#include <math.h>

#define NC   21
#define HW   (1024 * 1024)
#define NSEG 500
#define SEGC (NSEG * NC)   // 10500 floats = 42 KB
#define EPS  1e-5f

// ---------------------------------------------------------------------------
// Kernel 0: zero the segment accumulator in workspace (ws is poisoned 0xAA
// before every timed launch, so this must run each call).
// ---------------------------------------------------------------------------
__global__ void zero_seg_kernel(float* __restrict__ seg) {
    int i = blockIdx.x * blockDim.x + threadIdx.x;
    if (i < SEGC) seg[i] = 0.0f;
}

// ---------------------------------------------------------------------------
// Kernel 1: per-pixel softmax + log, accumulated per-segment.
// Per-block LDS table (42 KB -> 3 blocks/CU) to keep global atomic count at
// gridDim * 10500 instead of 21M.
// ---------------------------------------------------------------------------
__global__ __launch_bounds__(256) void seg_logsum_kernel(
        const float* __restrict__ q_logits,
        const int*   __restrict__ sp_map,
        float*       __restrict__ seg) {
    __shared__ float lseg[SEGC];
    for (int i = threadIdx.x; i < SEGC; i += 256) lseg[i] = 0.0f;
    __syncthreads();

    const int stride = gridDim.x * 256;
    for (int p = blockIdx.x * 256 + threadIdx.x; p < HW; p += stride) {
        float x[NC];
        float m = -INFINITY;
        #pragma unroll
        for (int c = 0; c < NC; ++c) {
            x[c] = q_logits[c * HW + p];   // coalesced per channel
            m = fmaxf(m, x[c]);
        }
        float Z = 0.0f;
        #pragma unroll
        for (int c = 0; c < NC; ++c) {
            x[c] = __expf(x[c] - m);
            Z += x[c];
        }
        const float rZ = 1.0f / Z;
        const int s = sp_map[p] * NC;
        #pragma unroll
        for (int c = 0; c < NC; ++c) {
            float q = x[c] * rZ;
            atomicAdd(&lseg[s + c], __logf(q + EPS));
        }
    }

    __syncthreads();
    for (int i = threadIdx.x; i < SEGC; i += 256) {
        float v = lseg[i];
        if (v != 0.0f) atomicAdd(&seg[i], v);   // device-scope by default
    }
}

// ---------------------------------------------------------------------------
// Kernel 2: recompute softmax, gather segment sums, epilogue, write output.
// ---------------------------------------------------------------------------
__global__ __launch_bounds__(256) void epilogue_kernel(
        const float* __restrict__ q_logits,
        const int*   __restrict__ sp_map,
        const float* __restrict__ seg,
        const float* __restrict__ lw,    // (2, NC)
        const float* __restrict__ hwt,   // (2,)
        float*       __restrict__ out) {
    const int p = blockIdx.x * 256 + threadIdx.x;
    if (p >= HW) return;

    float x[NC];
    float m = -INFINITY;
    #pragma unroll
    for (int c = 0; c < NC; ++c) {
        x[c] = q_logits[c * HW + p];
        m = fmaxf(m, x[c]);
    }
    float Z = 0.0f;
    #pragma unroll
    for (int c = 0; c < NC; ++c) {
        x[c] = __expf(x[c] - m);
        Z += x[c];
    }
    const float rZ = 1.0f / Z;
    const int s = sp_map[p] * NC;
    const float hw0 = hwt[0];
    const float hw1 = hwt[1];

    #pragma unroll
    for (int c = 0; c < NC; ++c) {
        float q = x[c] * rZ;
        float B = seg[s + c];                       // 42 KB table, L2-resident
        float qm = (q == 0.0f) ? 1.0f : q;          // q_values_modified
        float denom = __logf(qm + EPS);
        float f_sp  = __expf(B - denom);
        float f_att = __expf((float)(NSEG - 1) * B - denom);
        float o = lw[c]      * f_sp  + hw0 * (1.0f - f_sp)
                + lw[NC + c] * f_att + hw1 * (1.0f - f_att);
        out[c * HW + p] = o;                        // coalesced per channel
    }
}

// ---------------------------------------------------------------------------
extern "C" void kernel_launch(void* const* d_in, const int* in_sizes, int n_in,
                              void* d_out, int out_size, void* d_ws, size_t ws_size,
                              hipStream_t stream) {
    const float* q_logits = (const float*)d_in[0];   // (21,1024,1024) f32
    const float* lw       = (const float*)d_in[1];   // (2,21) f32
    const float* hwt      = (const float*)d_in[2];   // (2,)  f32
    const int*   sp_map   = (const int*)  d_in[3];   // (1024,1024) i32
    float* out = (float*)d_out;
    float* seg = (float*)d_ws;                       // 42 KB accumulator

    zero_seg_kernel<<<(SEGC + 255) / 256, 256, 0, stream>>>(seg);
    // 768 blocks = 3/CU (LDS-limited), grid-stride over pixels.
    seg_logsum_kernel<<<768, 256, 0, stream>>>(q_logits, sp_map, seg);
    epilogue_kernel<<<HW / 256, 256, 0, stream>>>(q_logits, sp_map, seg, lw, hwt, out);
}